// Round 1
// baseline (3623.544 us; speedup 1.0000x reference)
//
#include <hip/hip_runtime.h>
#include <cstdint>

#define NEG_SLOPE 0.2f
#define EPSV 1e-16f

// ---------------- Layer 1: h1 = x@W1 (N,128)->(N,64), alpha_src/dst per (n,h) ----------------
__global__ __launch_bounds__(256) void gemm1_alpha(
    const float* __restrict__ x, const float* __restrict__ W1,
    const float* __restrict__ aS, const float* __restrict__ aD,
    float* __restrict__ h1, float* __restrict__ as1, float* __restrict__ ad1, int N)
{
    __shared__ float Ws[128 * 64];
    __shared__ float xs[4][128];
    int t = threadIdx.x;
    for (int i = t; i < 128 * 64; i += 256) Ws[i] = W1[i];
    int n0 = blockIdx.x * 4;
    for (int i = t; i < 4 * 128; i += 256) {
        int r = i >> 7, c = i & 127;
        int n = n0 + r;
        xs[r][c] = (n < N) ? x[(size_t)n * 128 + c] : 0.f;
    }
    __syncthreads();
    int local = t >> 6;   // node within block (one wave per node)
    int col = t & 63;     // output col = h*8 + d
    int n = n0 + local;
    float acc = 0.f;
#pragma unroll
    for (int k = 0; k < 128; ++k) acc = fmaf(xs[local][k], Ws[k * 64 + col], acc);
    // per-head (groups of 8 lanes) reduction of acc * a[h,d]
    float s = acc * aS[col];
    float d = acc * aD[col];
#pragma unroll
    for (int off = 1; off < 8; off <<= 1) {
        s += __shfl_xor(s, off, 64);
        d += __shfl_xor(d, off, 64);
    }
    if (n < N) {
        h1[(size_t)n * 64 + col] = acc;
        if ((col & 7) == 0) {
            as1[n * 8 + (col >> 3)] = s;
            ad1[n * 8 + (col >> 3)] = d;
        }
    }
}

// ---------------- Layer 1 edge pass: one thread per (edge, head) ----------------
__global__ __launch_bounds__(256) void edge_pass1(
    const int* __restrict__ srcs, const int* __restrict__ dsts,
    const float* __restrict__ as1, const float* __restrict__ ad1,
    const float* __restrict__ h1,
    float* __restrict__ denom, float* __restrict__ msg, int E, int Et)
{
    long long tid = (long long)blockIdx.x * 256 + threadIdx.x;
    if (tid >= (long long)Et * 8) return;
    int i = (int)(tid >> 3);
    int h = (int)(tid & 7);
    int s, dn;
    if (i < E) { s = srcs[i]; dn = dsts[i]; }
    else       { s = i - E;   dn = s; }           // self-loop
    float e = as1[s * 8 + h] + ad1[dn * 8 + h];
    e = (e > 0.f) ? e : NEG_SLOPE * e;
    float w = __expf(e);
    atomicAdd(&denom[dn * 8 + h], w);
    const float* hp = &h1[(size_t)s * 64 + h * 8];
    float* mp = &msg[(size_t)dn * 64 + h * 8];
#pragma unroll
    for (int dd = 0; dd < 8; ++dd) atomicAdd(&mp[dd], hp[dd] * w);
}

// ---------------- Layer 1 finalize: normalize + bias + ELU (in-place msg -> helu) ----------------
__global__ __launch_bounds__(256) void finalize1(
    float* __restrict__ msg, const float* __restrict__ denom,
    const float* __restrict__ bias1, int N)
{
    int idx = blockIdx.x * 256 + threadIdx.x;
    if (idx >= N * 64) return;
    int n = idx >> 6, j = idx & 63;
    float v = msg[idx] / (denom[n * 8 + (j >> 3)] + EPSV) + bias1[j];
    msg[idx] = (v > 0.f) ? v : (__expf(v) - 1.f);
}

// ---------------- Layer 2: h2 = helu@W2 (N,64)->(N,40), scalar alphas ----------------
__global__ __launch_bounds__(256) void gemm2_alpha(
    const float* __restrict__ helu, const float* __restrict__ W2,
    const float* __restrict__ aS, const float* __restrict__ aD,
    float* __restrict__ h2, float* __restrict__ as2, float* __restrict__ ad2, int N)
{
    __shared__ float Ws[64 * 40];
    __shared__ float xs[4][64];
    int t = threadIdx.x;
    for (int i = t; i < 64 * 40; i += 256) Ws[i] = W2[i];
    int n0 = blockIdx.x * 4;
    for (int i = t; i < 4 * 64; i += 256) {
        int r = i >> 6, c = i & 63;
        int n = n0 + r;
        xs[r][c] = (n < N) ? helu[(size_t)n * 64 + c] : 0.f;
    }
    __syncthreads();
    int local = t >> 6;  // one wave per node
    int c = t & 63;
    int n = n0 + local;
    float acc = 0.f;
    if (c < 40) {
#pragma unroll
        for (int k = 0; k < 64; ++k) acc = fmaf(xs[local][k], Ws[k * 40 + c], acc);
    }
    float s = (c < 40) ? acc * aS[c] : 0.f;
    float d = (c < 40) ? acc * aD[c] : 0.f;
#pragma unroll
    for (int off = 1; off < 64; off <<= 1) {
        s += __shfl_xor(s, off, 64);
        d += __shfl_xor(d, off, 64);
    }
    if (n < N) {
        if (c < 40) h2[(size_t)n * 40 + c] = acc;
        if (c == 0) { as2[n] = s; ad2[n] = d; }
    }
}

// ---------------- Layer 2 edge pass: 8 lanes per edge, 5 cols each ----------------
__global__ __launch_bounds__(256) void edge_pass2(
    const int* __restrict__ srcs, const int* __restrict__ dsts,
    const float* __restrict__ as2, const float* __restrict__ ad2,
    const float* __restrict__ h2,
    float* __restrict__ denom2, float* __restrict__ out, int E, int Et)
{
    long long tid = (long long)blockIdx.x * 256 + threadIdx.x;
    if (tid >= (long long)Et * 8) return;
    int i = (int)(tid >> 3);
    int j = (int)(tid & 7);
    int s, dn;
    if (i < E) { s = srcs[i]; dn = dsts[i]; }
    else       { s = i - E;   dn = s; }
    float e = as2[s] + ad2[dn];
    e = (e > 0.f) ? e : NEG_SLOPE * e;
    float w = __expf(e);
    if (j == 0) atomicAdd(&denom2[dn], w);
#pragma unroll
    for (int c = j; c < 40; c += 8)
        atomicAdd(&out[(size_t)dn * 40 + c], h2[(size_t)s * 40 + c] * w);
}

// ---------------- Layer 2 finalize (in-place on d_out) ----------------
__global__ __launch_bounds__(256) void finalize2(
    float* __restrict__ out, const float* __restrict__ denom2,
    const float* __restrict__ bias2, int N)
{
    int idx = blockIdx.x * 256 + threadIdx.x;
    if (idx >= N * 40) return;
    int n = idx / 40, c = idx - n * 40;
    out[idx] = out[idx] / (denom2[n] + EPSV) + bias2[c];
}

extern "C" void kernel_launch(void* const* d_in, const int* in_sizes, int n_in,
                              void* d_out, int out_size, void* d_ws, size_t ws_size,
                              hipStream_t stream)
{
    const float* x   = (const float*)d_in[0];
    const int*   ei  = (const int*)d_in[1];
    // d_in[2] = edge_attr, unused by the reference computation
    const float* W1  = (const float*)d_in[3];
    const float* aS1 = (const float*)d_in[4];
    const float* aD1 = (const float*)d_in[5];
    const float* b1  = (const float*)d_in[6];
    const float* W2  = (const float*)d_in[7];
    const float* aS2 = (const float*)d_in[8];
    const float* aD2 = (const float*)d_in[9];
    const float* b2  = (const float*)d_in[10];

    int N  = in_sizes[0] / 128;
    int E  = in_sizes[1] / 2;
    int Et = E + N;

    float* ws    = (float*)d_ws;
    float* h1    = ws;                         // N*64
    float* as1   = h1   + (size_t)N * 64;      // N*8
    float* ad1   = as1  + (size_t)N * 8;       // N*8
    float* den1  = ad1  + (size_t)N * 8;       // N*8
    float* msg   = den1 + (size_t)N * 8;       // N*64 (reused as helu)
    float* h2    = msg  + (size_t)N * 64;      // N*40
    float* as2   = h2   + (size_t)N * 40;      // N
    float* ad2   = as2  + (size_t)N;           // N
    float* den2  = ad2  + (size_t)N;           // N
    float* out   = (float*)d_out;

    hipMemsetAsync(den1, 0, (size_t)N * 8 * sizeof(float), stream);
    hipMemsetAsync(msg,  0, (size_t)N * 64 * sizeof(float), stream);
    hipMemsetAsync(den2, 0, (size_t)N * sizeof(float), stream);
    hipMemsetAsync(d_out, 0, (size_t)N * 40 * sizeof(float), stream);

    const int* srcs = ei;
    const int* dsts = ei + E;

    gemm1_alpha<<<(N + 3) / 4, 256, 0, stream>>>(x, W1, aS1, aD1, h1, as1, ad1, N);

    long long tot = (long long)Et * 8;
    int eblocks = (int)((tot + 255) / 256);
    edge_pass1<<<eblocks, 256, 0, stream>>>(srcs, dsts, as1, ad1, h1, den1, msg, E, Et);

    finalize1<<<(N * 64 + 255) / 256, 256, 0, stream>>>(msg, den1, b1, N);

    gemm2_alpha<<<(N + 3) / 4, 256, 0, stream>>>(msg, W2, aS2, aD2, h2, as2, ad2, N);

    edge_pass2<<<eblocks, 256, 0, stream>>>(srcs, dsts, as2, ad2, h2, den2, out, E, Et);

    finalize2<<<(N * 40 + 255) / 256, 256, 0, stream>>>(out, den2, b2, N);
}

// Round 2
// 630.378 us; speedup vs baseline: 5.7482x; 5.7482x over previous
//
#include <hip/hip_runtime.h>
#include <cstdint>

#define NEG_SLOPE 0.2f
#define EPSV 1e-16f

// ---------------- Layer 1 GEMM: h1 = x@W1 (N,128)->(N,64) + alpha logits ----------------
__global__ __launch_bounds__(256) void gemm1_alpha(
    const float* __restrict__ x, const float* __restrict__ W1,
    const float* __restrict__ aS, const float* __restrict__ aD,
    float* __restrict__ h1, float* __restrict__ as1, float* __restrict__ ad1, int N)
{
    __shared__ float Ws[128 * 64];
    __shared__ float xs[4][128];
    int t = threadIdx.x;
    for (int i = t; i < 128 * 64; i += 256) Ws[i] = W1[i];
    int n0 = blockIdx.x * 4;
    for (int i = t; i < 4 * 128; i += 256) {
        int r = i >> 7, c = i & 127;
        int n = n0 + r;
        xs[r][c] = (n < N) ? x[(size_t)n * 128 + c] : 0.f;
    }
    __syncthreads();
    int local = t >> 6;   // one wave per node
    int col = t & 63;     // col = h*8 + d
    int n = n0 + local;
    float acc = 0.f;
#pragma unroll
    for (int k = 0; k < 128; ++k) acc = fmaf(xs[local][k], Ws[k * 64 + col], acc);
    float s = acc * aS[col];
    float d = acc * aD[col];
#pragma unroll
    for (int off = 1; off < 8; off <<= 1) {
        s += __shfl_xor(s, off, 64);
        d += __shfl_xor(d, off, 64);
    }
    if (n < N) {
        h1[(size_t)n * 64 + col] = acc;
        if ((col & 7) == 0) {
            as1[n * 8 + (col >> 3)] = s;
            ad1[n * 8 + (col >> 3)] = d;
        }
    }
}

// ---------------- CSR build ----------------
__global__ __launch_bounds__(256) void k_deg(
    const int* __restrict__ dsts, int* __restrict__ deg, int E, int Et)
{
    int i = blockIdx.x * 256 + threadIdx.x;
    if (i >= Et) return;
    int dn = (i < E) ? dsts[i] : (i - E);
    atomicAdd(&deg[dn], 1);
}

// per-block (1024 elems) exclusive scan of deg -> row_ptr(local); block totals -> bsum
__global__ __launch_bounds__(256) void k_scan_local(
    const int* __restrict__ deg, int* __restrict__ row_ptr, int* __restrict__ bsum, int N)
{
    __shared__ int tsum[256];
    int b = blockIdx.x, t = threadIdx.x;
    int base = b * 1024 + t * 4;
    int v0, v1, v2, v3, s = 0;
    int d;
    v0 = s; d = (base + 0 < N) ? deg[base + 0] : 0; s += d;
    v1 = s; d = (base + 1 < N) ? deg[base + 1] : 0; s += d;
    v2 = s; d = (base + 2 < N) ? deg[base + 2] : 0; s += d;
    v3 = s; d = (base + 3 < N) ? deg[base + 3] : 0; s += d;
    tsum[t] = s;
    __syncthreads();
    for (int off = 1; off < 256; off <<= 1) {
        int y = (t >= off) ? tsum[t - off] : 0;
        __syncthreads();
        tsum[t] += y;
        __syncthreads();
    }
    int excl = tsum[t] - s;   // exclusive prefix of this thread within block
    if (base + 0 < N) row_ptr[base + 0] = excl + v0;
    if (base + 1 < N) row_ptr[base + 1] = excl + v1;
    if (base + 2 < N) row_ptr[base + 2] = excl + v2;
    if (base + 3 < N) row_ptr[base + 3] = excl + v3;
    if (t == 255) bsum[b] = tsum[255];
}

__global__ void k_scan_blocks(const int* __restrict__ bsum, int* __restrict__ boff,
                              int* __restrict__ row_ptr, int nb, int N, int Et)
{
    if (threadIdx.x == 0 && blockIdx.x == 0) {
        int run = 0;
        for (int b = 0; b < nb; ++b) { boff[b] = run; run += bsum[b]; }
        row_ptr[N] = Et;
    }
}

__global__ __launch_bounds__(256) void k_add_boff(
    int* __restrict__ row_ptr, int* __restrict__ cursor,
    const int* __restrict__ boff, int N)
{
    int i = blockIdx.x * 256 + threadIdx.x;
    if (i >= N) return;
    int r = row_ptr[i] + boff[i >> 10];
    row_ptr[i] = r;
    cursor[i] = r;
}

__global__ __launch_bounds__(256) void k_fill(
    const int* __restrict__ srcs, const int* __restrict__ dsts,
    int* __restrict__ cursor, int* __restrict__ colx, int E, int Et)
{
    int i = blockIdx.x * 256 + threadIdx.x;
    if (i >= Et) return;
    int s, dn;
    if (i < E) { s = srcs[i]; dn = dsts[i]; }
    else       { s = i - E;   dn = s; }
    int pos = atomicAdd(&cursor[dn], 1);
    colx[pos] = s;
}

// ---------------- Layer 1 gather: one wave per dst node, no atomics ----------------
__global__ __launch_bounds__(256) void gather1(
    const int* __restrict__ row_ptr, const int* __restrict__ colx,
    const float* __restrict__ as1, const float* __restrict__ ad1,
    const float* __restrict__ h1, const float* __restrict__ bias1,
    float* __restrict__ helu, int N)
{
    int wave = (blockIdx.x * 256 + threadIdx.x) >> 6;
    int lane = threadIdx.x & 63;
    if (wave >= N) return;
    int n = wave;
    int h = lane >> 3;
    float adn = ad1[n * 8 + h];
    int beg = row_ptr[n], end = row_ptr[n + 1];
    float acc = 0.f, wsum = 0.f;
    int s = colx[beg];
    for (int j = beg; j < end; ++j) {
        int snext = (j + 1 < end) ? colx[j + 1] : 0;
        float e = as1[s * 8 + h] + adn;
        e = (e > 0.f) ? e : NEG_SLOPE * e;
        float w = __expf(e);
        acc = fmaf(w, h1[(size_t)s * 64 + lane], acc);
        wsum += w;
        s = snext;
    }
    float v = acc / (wsum + EPSV) + bias1[lane];
    helu[(size_t)n * 64 + lane] = (v > 0.f) ? v : (__expf(v) - 1.f);
}

// ---------------- Layer 2 GEMM: h2 = helu@W2 (N,64)->(N,40), scalar alphas ----------------
__global__ __launch_bounds__(256) void gemm2_alpha(
    const float* __restrict__ helu, const float* __restrict__ W2,
    const float* __restrict__ aS, const float* __restrict__ aD,
    float* __restrict__ h2, float* __restrict__ as2, float* __restrict__ ad2, int N)
{
    __shared__ float Ws[64 * 40];
    __shared__ float xs[4][64];
    int t = threadIdx.x;
    for (int i = t; i < 64 * 40; i += 256) Ws[i] = W2[i];
    int n0 = blockIdx.x * 4;
    for (int i = t; i < 4 * 64; i += 256) {
        int r = i >> 6, c = i & 63;
        int n = n0 + r;
        xs[r][c] = (n < N) ? helu[(size_t)n * 64 + c] : 0.f;
    }
    __syncthreads();
    int local = t >> 6;
    int c = t & 63;
    int n = n0 + local;
    float acc = 0.f;
    if (c < 40) {
#pragma unroll
        for (int k = 0; k < 64; ++k) acc = fmaf(xs[local][k], Ws[k * 40 + c], acc);
    }
    float s = (c < 40) ? acc * aS[c] : 0.f;
    float d = (c < 40) ? acc * aD[c] : 0.f;
#pragma unroll
    for (int off = 1; off < 64; off <<= 1) {
        s += __shfl_xor(s, off, 64);
        d += __shfl_xor(d, off, 64);
    }
    if (n < N) {
        if (c < 40) h2[(size_t)n * 40 + c] = acc;
        if (c == 0) { as2[n] = s; ad2[n] = d; }
    }
}

// ---------------- Layer 2 gather: one wave per dst node ----------------
__global__ __launch_bounds__(256) void gather2(
    const int* __restrict__ row_ptr, const int* __restrict__ colx,
    const float* __restrict__ as2, const float* __restrict__ ad2,
    const float* __restrict__ h2, const float* __restrict__ bias2,
    float* __restrict__ out, int N)
{
    int wave = (blockIdx.x * 256 + threadIdx.x) >> 6;
    int lane = threadIdx.x & 63;
    if (wave >= N) return;
    int n = wave;
    float adn = ad2[n];
    int beg = row_ptr[n], end = row_ptr[n + 1];
    float acc = 0.f, wsum = 0.f;
    int s = colx[beg];
    for (int j = beg; j < end; ++j) {
        int snext = (j + 1 < end) ? colx[j + 1] : 0;
        float e = as2[s] + adn;
        e = (e > 0.f) ? e : NEG_SLOPE * e;
        float w = __expf(e);
        float hv = (lane < 40) ? h2[(size_t)s * 40 + lane] : 0.f;
        acc = fmaf(w, hv, acc);
        wsum += w;
        s = snext;
    }
    if (lane < 40)
        out[(size_t)n * 40 + lane] = acc / (wsum + EPSV) + bias2[lane];
}

extern "C" void kernel_launch(void* const* d_in, const int* in_sizes, int n_in,
                              void* d_out, int out_size, void* d_ws, size_t ws_size,
                              hipStream_t stream)
{
    const float* x   = (const float*)d_in[0];
    const int*   ei  = (const int*)d_in[1];
    const float* W1  = (const float*)d_in[3];
    const float* aS1 = (const float*)d_in[4];
    const float* aD1 = (const float*)d_in[5];
    const float* b1  = (const float*)d_in[6];
    const float* W2  = (const float*)d_in[7];
    const float* aS2 = (const float*)d_in[8];
    const float* aD2 = (const float*)d_in[9];
    const float* b2  = (const float*)d_in[10];

    int N  = in_sizes[0] / 128;
    int E  = in_sizes[1] / 2;
    int Et = E + N;

    // ---- workspace layout ----
    float* fws   = (float*)d_ws;
    float* h1    = fws;                        // N*64
    float* as1   = h1   + (size_t)N * 64;      // N*8
    float* ad1   = as1  + (size_t)N * 8;       // N*8
    float* helu  = ad1  + (size_t)N * 8;       // N*64
    float* h2    = helu + (size_t)N * 64;      // N*40
    float* as2   = h2   + (size_t)N * 40;      // N
    float* ad2   = as2  + (size_t)N;           // N
    int*   iws   = (int*)(ad2 + (size_t)N);
    int*   deg     = iws;                      // N
    int*   row_ptr = deg + N;                  // N+1
    int*   cursor  = row_ptr + N + 1;          // N
    int*   bsum    = cursor + N;               // 64
    int*   boff    = bsum + 64;                // 64
    int*   colx    = boff + 64;                // Et
    float* out     = (float*)d_out;

    const int* srcs = ei;
    const int* dsts = ei + E;

    int nb = (N + 1023) / 1024;
    int eb = (Et + 255) / 256;
    int nb256 = (N + 255) / 256;

    // ---- CSR build ----
    hipMemsetAsync(deg, 0, (size_t)N * sizeof(int), stream);
    k_deg<<<eb, 256, 0, stream>>>(dsts, deg, E, Et);
    k_scan_local<<<nb, 256, 0, stream>>>(deg, row_ptr, bsum, N);
    k_scan_blocks<<<1, 64, 0, stream>>>(bsum, boff, row_ptr, nb, N, Et);
    k_add_boff<<<nb256, 256, 0, stream>>>(row_ptr, cursor, boff, N);
    k_fill<<<eb, 256, 0, stream>>>(srcs, dsts, cursor, colx, E, Et);

    // ---- Layer 1 ----
    gemm1_alpha<<<(N + 3) / 4, 256, 0, stream>>>(x, W1, aS1, aD1, h1, as1, ad1, N);
    gather1<<<(N * 64 + 255) / 256, 256, 0, stream>>>(row_ptr, colx, as1, ad1, h1, b1, helu, N);

    // ---- Layer 2 ----
    gemm2_alpha<<<(N + 3) / 4, 256, 0, stream>>>(helu, W2, aS2, aD2, h2, as2, ad2, N);
    gather2<<<(N * 64 + 255) / 256, 256, 0, stream>>>(row_ptr, colx, as2, ad2, h2, b2, out, N);
}

// Round 3
// 451.828 us; speedup vs baseline: 8.0197x; 1.3952x over previous
//
#include <hip/hip_runtime.h>
#include <hip/hip_fp16.h>
#include <cstdint>

#define NEG_SLOPE 0.2f
#define EPSV 1e-16f

// ---------------- Layer 1 GEMM: h1 = x@W1 (N,128)->(N,64) + alpha logits ----------------
// 16 nodes per block (4 per wave) to amortize W1 LDS staging.
__global__ __launch_bounds__(256) void gemm1_alpha(
    const float* __restrict__ x, const float* __restrict__ W1,
    const float* __restrict__ aS, const float* __restrict__ aD,
    __half* __restrict__ h1h, float* __restrict__ as1, float* __restrict__ ad1, int N)
{
    __shared__ float Ws[128 * 64];   // 32 KB
    __shared__ float xs[16][128];    // 8 KB
    int t = threadIdx.x;
    for (int i = t; i < 128 * 64; i += 256) Ws[i] = W1[i];
    int n0 = blockIdx.x * 16;
    for (int i = t; i < 16 * 128; i += 256) {
        int r = i >> 7, c = i & 127;
        int n = n0 + r;
        xs[r][c] = (n < N) ? x[(size_t)n * 128 + c] : 0.f;
    }
    __syncthreads();
    int wv = t >> 6;
    int col = t & 63;     // col = h*8 + d
    float asc = aS[col], adc = aD[col];
#pragma unroll
    for (int r = 0; r < 4; ++r) {
        int local = wv * 4 + r;
        int n = n0 + local;
        float acc = 0.f;
#pragma unroll
        for (int k = 0; k < 128; ++k) acc = fmaf(xs[local][k], Ws[k * 64 + col], acc);
        float s = acc * asc;
        float d = acc * adc;
#pragma unroll
        for (int off = 1; off < 8; off <<= 1) {
            s += __shfl_xor(s, off, 64);
            d += __shfl_xor(d, off, 64);
        }
        if (n < N) {
            h1h[(size_t)n * 64 + col] = __float2half(acc);
            if ((col & 7) == 0) {
                as1[n * 8 + (col >> 3)] = s;
                ad1[n * 8 + (col >> 3)] = d;
            }
        }
    }
}

// ---------------- CSR build ----------------
__global__ __launch_bounds__(256) void k_deg(
    const int* __restrict__ dsts, int* __restrict__ deg, int E, int Et)
{
    int i = blockIdx.x * 256 + threadIdx.x;
    if (i >= Et) return;
    int dn = (i < E) ? dsts[i] : (i - E);
    atomicAdd(&deg[dn], 1);
}

__global__ __launch_bounds__(256) void k_scan_local(
    const int* __restrict__ deg, int* __restrict__ row_ptr, int* __restrict__ bsum, int N)
{
    __shared__ int tsum[256];
    int b = blockIdx.x, t = threadIdx.x;
    int base = b * 1024 + t * 4;
    int v0, v1, v2, v3, s = 0;
    int d;
    v0 = s; d = (base + 0 < N) ? deg[base + 0] : 0; s += d;
    v1 = s; d = (base + 1 < N) ? deg[base + 1] : 0; s += d;
    v2 = s; d = (base + 2 < N) ? deg[base + 2] : 0; s += d;
    v3 = s; d = (base + 3 < N) ? deg[base + 3] : 0; s += d;
    tsum[t] = s;
    __syncthreads();
    for (int off = 1; off < 256; off <<= 1) {
        int y = (t >= off) ? tsum[t - off] : 0;
        __syncthreads();
        tsum[t] += y;
        __syncthreads();
    }
    int excl = tsum[t] - s;
    if (base + 0 < N) row_ptr[base + 0] = excl + v0;
    if (base + 1 < N) row_ptr[base + 1] = excl + v1;
    if (base + 2 < N) row_ptr[base + 2] = excl + v2;
    if (base + 3 < N) row_ptr[base + 3] = excl + v3;
    if (t == 255) bsum[b] = tsum[255];
}

__global__ void k_scan_blocks(const int* __restrict__ bsum, int* __restrict__ boff,
                              int* __restrict__ row_ptr, int nb, int N, int Et)
{
    if (threadIdx.x == 0 && blockIdx.x == 0) {
        int run = 0;
        for (int b = 0; b < nb; ++b) { boff[b] = run; run += bsum[b]; }
        row_ptr[N] = Et;
    }
}

__global__ __launch_bounds__(256) void k_add_boff(
    int* __restrict__ row_ptr, int* __restrict__ cursor,
    const int* __restrict__ boff, int N)
{
    int i = blockIdx.x * 256 + threadIdx.x;
    if (i >= N) return;
    int r = row_ptr[i] + boff[i >> 10];
    row_ptr[i] = r;
    cursor[i] = r;
}

__global__ __launch_bounds__(256) void k_fill(
    const int* __restrict__ srcs, const int* __restrict__ dsts,
    int* __restrict__ cursor, int* __restrict__ colx, int E, int Et)
{
    int i = blockIdx.x * 256 + threadIdx.x;
    if (i >= Et) return;
    int s, dn;
    if (i < E) { s = srcs[i]; dn = dsts[i]; }
    else       { s = i - E;   dn = s; }
    int pos = atomicAdd(&cursor[dn], 1);
    colx[pos] = s;
}

// ---------------- Layer 1 gather: one wave per dst node, unroll-4, fp16 h ----------------
__global__ __launch_bounds__(256) void gather1(
    const int* __restrict__ row_ptr, const int* __restrict__ colx,
    const float* __restrict__ as1, const float* __restrict__ ad1,
    const __half* __restrict__ h1h, const float* __restrict__ bias1,
    float* __restrict__ helu, int N)
{
    int wave = (blockIdx.x * 256 + threadIdx.x) >> 6;
    int lane = threadIdx.x & 63;
    if (wave >= N) return;
    int n = wave;
    int h = lane >> 3;
    float adn = ad1[n * 8 + h];
    int beg = row_ptr[n], end = row_ptr[n + 1];
    float acc = 0.f, wsum = 0.f;
    int j = beg;
    for (; j + 4 <= end; j += 4) {
        int s0 = colx[j], s1 = colx[j + 1], s2 = colx[j + 2], s3 = colx[j + 3];
        float a0 = as1[s0 * 8 + h];
        float a1 = as1[s1 * 8 + h];
        float a2 = as1[s2 * 8 + h];
        float a3 = as1[s3 * 8 + h];
        float h0 = __half2float(h1h[(size_t)s0 * 64 + lane]);
        float h1v = __half2float(h1h[(size_t)s1 * 64 + lane]);
        float h2v = __half2float(h1h[(size_t)s2 * 64 + lane]);
        float h3v = __half2float(h1h[(size_t)s3 * 64 + lane]);
        float e0 = a0 + adn; e0 = (e0 > 0.f) ? e0 : NEG_SLOPE * e0;
        float e1 = a1 + adn; e1 = (e1 > 0.f) ? e1 : NEG_SLOPE * e1;
        float e2 = a2 + adn; e2 = (e2 > 0.f) ? e2 : NEG_SLOPE * e2;
        float e3 = a3 + adn; e3 = (e3 > 0.f) ? e3 : NEG_SLOPE * e3;
        float w0 = __expf(e0), w1 = __expf(e1), w2 = __expf(e2), w3 = __expf(e3);
        acc = fmaf(w0, h0, acc);
        acc = fmaf(w1, h1v, acc);
        acc = fmaf(w2, h2v, acc);
        acc = fmaf(w3, h3v, acc);
        wsum += (w0 + w1) + (w2 + w3);
    }
    for (; j < end; ++j) {
        int s = colx[j];
        float e = as1[s * 8 + h] + adn;
        e = (e > 0.f) ? e : NEG_SLOPE * e;
        float w = __expf(e);
        acc = fmaf(w, __half2float(h1h[(size_t)s * 64 + lane]), acc);
        wsum += w;
    }
    float v = acc / (wsum + EPSV) + bias1[lane];
    helu[(size_t)n * 64 + lane] = (v > 0.f) ? v : (__expf(v) - 1.f);
}

// ---------------- Layer 2 GEMM: h2 = helu@W2 (N,64)->(N,40) ----------------
__global__ __launch_bounds__(256) void gemm2_alpha(
    const float* __restrict__ helu, const float* __restrict__ W2,
    const float* __restrict__ aS, const float* __restrict__ aD,
    __half* __restrict__ h2h, float* __restrict__ as2, float* __restrict__ ad2, int N)
{
    __shared__ float Ws[64 * 40];    // 10 KB
    __shared__ float xs[16][64];     // 4 KB
    int t = threadIdx.x;
    for (int i = t; i < 64 * 40; i += 256) Ws[i] = W2[i];
    int n0 = blockIdx.x * 16;
    for (int i = t; i < 16 * 64; i += 256) {
        int r = i >> 6, c = i & 63;
        int n = n0 + r;
        xs[r][c] = (n < N) ? helu[(size_t)n * 64 + c] : 0.f;
    }
    __syncthreads();
    int wv = t >> 6;
    int c = t & 63;
    float asc = (c < 40) ? aS[c] : 0.f;
    float adc = (c < 40) ? aD[c] : 0.f;
#pragma unroll
    for (int r = 0; r < 4; ++r) {
        int local = wv * 4 + r;
        int n = n0 + local;
        float acc = 0.f;
        if (c < 40) {
#pragma unroll
            for (int k = 0; k < 64; ++k) acc = fmaf(xs[local][k], Ws[k * 40 + c], acc);
        }
        float s = acc * asc;
        float d = acc * adc;
#pragma unroll
        for (int off = 1; off < 64; off <<= 1) {
            s += __shfl_xor(s, off, 64);
            d += __shfl_xor(d, off, 64);
        }
        if (n < N) {
            if (c < 40) h2h[(size_t)n * 40 + c] = __float2half(acc);
            if (c == 0) { as2[n] = s; ad2[n] = d; }
        }
    }
}

// ---------------- Layer 2 gather: one wave per dst node, unroll-4, fp16 h2 ----------------
__global__ __launch_bounds__(256) void gather2(
    const int* __restrict__ row_ptr, const int* __restrict__ colx,
    const float* __restrict__ as2, const float* __restrict__ ad2,
    const __half* __restrict__ h2h, const float* __restrict__ bias2,
    float* __restrict__ out, int N)
{
    int wave = (blockIdx.x * 256 + threadIdx.x) >> 6;
    int lane = threadIdx.x & 63;
    if (wave >= N) return;
    int n = wave;
    float adn = ad2[n];
    int beg = row_ptr[n], end = row_ptr[n + 1];
    float acc = 0.f, wsum = 0.f;
    bool act = (lane < 40);
    int j = beg;
    for (; j + 4 <= end; j += 4) {
        int s0 = colx[j], s1 = colx[j + 1], s2 = colx[j + 2], s3 = colx[j + 3];
        float a0 = as2[s0], a1 = as2[s1], a2 = as2[s2], a3 = as2[s3];
        float h0 = act ? __half2float(h2h[(size_t)s0 * 40 + lane]) : 0.f;
        float h1v = act ? __half2float(h2h[(size_t)s1 * 40 + lane]) : 0.f;
        float h2v = act ? __half2float(h2h[(size_t)s2 * 40 + lane]) : 0.f;
        float h3v = act ? __half2float(h2h[(size_t)s3 * 40 + lane]) : 0.f;
        float e0 = a0 + adn; e0 = (e0 > 0.f) ? e0 : NEG_SLOPE * e0;
        float e1 = a1 + adn; e1 = (e1 > 0.f) ? e1 : NEG_SLOPE * e1;
        float e2 = a2 + adn; e2 = (e2 > 0.f) ? e2 : NEG_SLOPE * e2;
        float e3 = a3 + adn; e3 = (e3 > 0.f) ? e3 : NEG_SLOPE * e3;
        float w0 = __expf(e0), w1 = __expf(e1), w2 = __expf(e2), w3 = __expf(e3);
        acc = fmaf(w0, h0, acc);
        acc = fmaf(w1, h1v, acc);
        acc = fmaf(w2, h2v, acc);
        acc = fmaf(w3, h3v, acc);
        wsum += (w0 + w1) + (w2 + w3);
    }
    for (; j < end; ++j) {
        int s = colx[j];
        float e = as2[s] + adn;
        e = (e > 0.f) ? e : NEG_SLOPE * e;
        float w = __expf(e);
        float hv = act ? __half2float(h2h[(size_t)s * 40 + lane]) : 0.f;
        acc = fmaf(w, hv, acc);
        wsum += w;
    }
    if (act)
        out[(size_t)n * 40 + lane] = acc / (wsum + EPSV) + bias2[lane];
}

extern "C" void kernel_launch(void* const* d_in, const int* in_sizes, int n_in,
                              void* d_out, int out_size, void* d_ws, size_t ws_size,
                              hipStream_t stream)
{
    const float* x   = (const float*)d_in[0];
    const int*   ei  = (const int*)d_in[1];
    const float* W1  = (const float*)d_in[3];
    const float* aS1 = (const float*)d_in[4];
    const float* aD1 = (const float*)d_in[5];
    const float* b1  = (const float*)d_in[6];
    const float* W2  = (const float*)d_in[7];
    const float* aS2 = (const float*)d_in[8];
    const float* aD2 = (const float*)d_in[9];
    const float* b2  = (const float*)d_in[10];

    int N  = in_sizes[0] / 128;
    int E  = in_sizes[1] / 2;
    int Et = E + N;

    // ---- workspace layout ----
    float* fws   = (float*)d_ws;
    float* as1   = fws;                        // N*8
    float* ad1   = as1  + (size_t)N * 8;       // N*8
    float* helu  = ad1  + (size_t)N * 8;       // N*64
    float* as2   = helu + (size_t)N * 64;      // N
    float* ad2   = as2  + (size_t)N;           // N
    __half* h1h  = (__half*)(ad2 + (size_t)N); // N*64 halves
    __half* h2h  = h1h + (size_t)N * 64;       // N*40 halves
    int*   iws   = (int*)(h2h + (size_t)N * 40);
    int*   deg     = iws;                      // N
    int*   row_ptr = deg + N;                  // N+1
    int*   cursor  = row_ptr + N + 1;          // N
    int*   bsum    = cursor + N;               // 64
    int*   boff    = bsum + 64;                // 64
    int*   colx    = boff + 64;                // Et
    float* out     = (float*)d_out;

    const int* srcs = ei;
    const int* dsts = ei + E;

    int nb = (N + 1023) / 1024;
    int eb = (Et + 255) / 256;
    int nb256 = (N + 255) / 256;

    // ---- CSR build ----
    hipMemsetAsync(deg, 0, (size_t)N * sizeof(int), stream);
    k_deg<<<eb, 256, 0, stream>>>(dsts, deg, E, Et);
    k_scan_local<<<nb, 256, 0, stream>>>(deg, row_ptr, bsum, N);
    k_scan_blocks<<<1, 64, 0, stream>>>(bsum, boff, row_ptr, nb, N, Et);
    k_add_boff<<<nb256, 256, 0, stream>>>(row_ptr, cursor, boff, N);
    k_fill<<<eb, 256, 0, stream>>>(srcs, dsts, cursor, colx, E, Et);

    // ---- Layer 1 ----
    gemm1_alpha<<<(N + 15) / 16, 256, 0, stream>>>(x, W1, aS1, aD1, h1h, as1, ad1, N);
    gather1<<<(N * 64 + 255) / 256, 256, 0, stream>>>(row_ptr, colx, as1, ad1, h1h, b1, helu, N);

    // ---- Layer 2 ----
    gemm2_alpha<<<(N + 15) / 16, 256, 0, stream>>>(helu, W2, aS2, aD2, h2h, as2, ad2, N);
    gather2<<<(N * 64 + 255) / 256, 256, 0, stream>>>(row_ptr, colx, as2, ad2, h2h, b2, out, N);
}

// Round 4
// 323.213 us; speedup vs baseline: 11.2110x; 1.3979x over previous
//
#include <hip/hip_runtime.h>
#include <hip/hip_fp16.h>
#include <cstdint>

#define NEG_SLOPE 0.2f
#define EPSV 1e-16f

#define BIN_SHIFT 8
#define NODES_PER_BIN 256
#define MAXBINS 512
#define CHUNK 8192

// ---------------- Layer 1 GEMM: h1 = x@W1 (N,128)->(N,64) + alpha logits ----------------
__global__ __launch_bounds__(256) void gemm1_alpha(
    const float* __restrict__ x, const float* __restrict__ W1,
    const float* __restrict__ aS, const float* __restrict__ aD,
    __half* __restrict__ h1h, float* __restrict__ as1, float* __restrict__ ad1, int N)
{
    __shared__ float Ws[128 * 64];   // 32 KB
    __shared__ float xs[16][128];    // 8 KB
    int t = threadIdx.x;
    for (int i = t; i < 128 * 64; i += 256) Ws[i] = W1[i];
    int n0 = blockIdx.x * 16;
    for (int i = t; i < 16 * 128; i += 256) {
        int r = i >> 7, c = i & 127;
        int n = n0 + r;
        xs[r][c] = (n < N) ? x[(size_t)n * 128 + c] : 0.f;
    }
    __syncthreads();
    int wv = t >> 6;
    int col = t & 63;     // col = h*8 + d
    float asc = aS[col], adc = aD[col];
#pragma unroll
    for (int r = 0; r < 4; ++r) {
        int local = wv * 4 + r;
        int n = n0 + local;
        float acc = 0.f;
#pragma unroll
        for (int k = 0; k < 128; ++k) acc = fmaf(xs[local][k], Ws[k * 64 + col], acc);
        float s = acc * asc;
        float d = acc * adc;
#pragma unroll
        for (int off = 1; off < 8; off <<= 1) {
            s += __shfl_xor(s, off, 64);
            d += __shfl_xor(d, off, 64);
        }
        if (n < N) {
            h1h[(size_t)n * 64 + col] = __float2half(acc);
            if ((col & 7) == 0) {
                as1[n * 8 + (col >> 3)] = s;
                ad1[n * 8 + (col >> 3)] = d;
            }
        }
    }
}

// ---------------- CSR build: binned counting sort ----------------
__global__ __launch_bounds__(256) void binhist(
    const int* __restrict__ dsts, int* __restrict__ bincnt, int E, int Et, int nbins)
{
    __shared__ int lh[MAXBINS];
    int t = threadIdx.x;
    for (int i = t; i < nbins; i += 256) lh[i] = 0;
    __syncthreads();
    int base = blockIdx.x * CHUNK;
#pragma unroll
    for (int r = 0; r < CHUNK / 256; ++r) {
        int i = base + r * 256 + t;
        if (i < Et) {
            int dn = (i < E) ? dsts[i] : (i - E);
            atomicAdd(&lh[dn >> BIN_SHIFT], 1);
        }
    }
    __syncthreads();
    for (int i = t; i < nbins; i += 256)
        if (lh[i]) atomicAdd(&bincnt[i], lh[i]);
}

__global__ void binscan(const int* __restrict__ bincnt, int* __restrict__ binoff,
                        int* __restrict__ bincur, int* __restrict__ row_ptr,
                        int nbins, int N, int Et)
{
    if (threadIdx.x == 0 && blockIdx.x == 0) {
        int run = 0;
        for (int b = 0; b < nbins; ++b) { binoff[b] = run; bincur[b] = run; run += bincnt[b]; }
        binoff[nbins] = run;
        row_ptr[N] = Et;
    }
}

__global__ __launch_bounds__(256) void binscatter(
    const int* __restrict__ srcs, const int* __restrict__ dsts,
    int* __restrict__ bincur, unsigned int* __restrict__ binned, int E, int Et, int nbins)
{
    __shared__ int lh[MAXBINS];
    __shared__ int gbase[MAXBINS];
    __shared__ int lcur[MAXBINS];
    int t = threadIdx.x;
    for (int i = t; i < nbins; i += 256) lh[i] = 0;
    __syncthreads();
    int base = blockIdx.x * CHUNK;
#pragma unroll
    for (int r = 0; r < CHUNK / 256; ++r) {
        int i = base + r * 256 + t;
        if (i < Et) {
            int dn = (i < E) ? dsts[i] : (i - E);
            atomicAdd(&lh[dn >> BIN_SHIFT], 1);
        }
    }
    __syncthreads();
    for (int i = t; i < nbins; i += 256) {
        gbase[i] = lh[i] ? atomicAdd(&bincur[i], lh[i]) : 0;
        lcur[i] = 0;
    }
    __syncthreads();
#pragma unroll
    for (int r = 0; r < CHUNK / 256; ++r) {
        int i = base + r * 256 + t;
        if (i < Et) {
            int s, dn;
            if (i < E) { s = srcs[i]; dn = dsts[i]; }
            else       { s = i - E;   dn = s; }
            int b = dn >> BIN_SHIFT;
            int li = atomicAdd(&lcur[b], 1);
            binned[gbase[b] + li] = ((unsigned)(dn & (NODES_PER_BIN - 1)) << 24) | (unsigned)s;
        }
    }
}

__global__ __launch_bounds__(256) void binsort(
    const unsigned int* __restrict__ binned, const int* __restrict__ binoff,
    int* __restrict__ row_ptr, int* __restrict__ colx, int N, int nbins)
{
    __shared__ int lh[NODES_PER_BIN];
    __shared__ int lcur[NODES_PER_BIN];
    int b = blockIdx.x, t = threadIdx.x;
    int beg = binoff[b], end = binoff[b + 1];
    lh[t] = 0;
    __syncthreads();
    for (int j = beg + t; j < end; j += 256)
        atomicAdd(&lh[binned[j] >> 24], 1);
    __syncthreads();
    int own = lh[t];
    for (int off = 1; off < 256; off <<= 1) {
        int y = (t >= off) ? lh[t - off] : 0;
        __syncthreads();
        lh[t] += y;
        __syncthreads();
    }
    int excl = lh[t] - own;
    int gnode = (b << BIN_SHIFT) + t;
    if (gnode < N) row_ptr[gnode] = beg + excl;
    lcur[t] = excl;
    __syncthreads();
    for (int j = beg + t; j < end; j += 256) {
        unsigned p = binned[j];
        int pos = atomicAdd(&lcur[p >> 24], 1);
        colx[beg + pos] = (int)(p & 0xFFFFFF);
    }
}

// ---------------- Layer 1 gather: one wave per dst node, unroll-4, fp16 h ----------------
__global__ __launch_bounds__(256) void gather1(
    const int* __restrict__ row_ptr, const int* __restrict__ colx,
    const float* __restrict__ as1, const float* __restrict__ ad1,
    const __half* __restrict__ h1h, const float* __restrict__ bias1,
    float* __restrict__ helu, int N)
{
    int wave = (blockIdx.x * 256 + threadIdx.x) >> 6;
    int lane = threadIdx.x & 63;
    if (wave >= N) return;
    int n = wave;
    int h = lane >> 3;
    float adn = ad1[n * 8 + h];
    int beg = row_ptr[n], end = row_ptr[n + 1];
    float acc = 0.f, wsum = 0.f;
    int j = beg;
    for (; j + 4 <= end; j += 4) {
        int s0 = colx[j], s1 = colx[j + 1], s2 = colx[j + 2], s3 = colx[j + 3];
        float a0 = as1[s0 * 8 + h];
        float a1 = as1[s1 * 8 + h];
        float a2 = as1[s2 * 8 + h];
        float a3 = as1[s3 * 8 + h];
        float h0 = __half2float(h1h[(size_t)s0 * 64 + lane]);
        float h1v = __half2float(h1h[(size_t)s1 * 64 + lane]);
        float h2v = __half2float(h1h[(size_t)s2 * 64 + lane]);
        float h3v = __half2float(h1h[(size_t)s3 * 64 + lane]);
        float e0 = a0 + adn; e0 = (e0 > 0.f) ? e0 : NEG_SLOPE * e0;
        float e1 = a1 + adn; e1 = (e1 > 0.f) ? e1 : NEG_SLOPE * e1;
        float e2 = a2 + adn; e2 = (e2 > 0.f) ? e2 : NEG_SLOPE * e2;
        float e3 = a3 + adn; e3 = (e3 > 0.f) ? e3 : NEG_SLOPE * e3;
        float w0 = __expf(e0), w1 = __expf(e1), w2 = __expf(e2), w3 = __expf(e3);
        acc = fmaf(w0, h0, acc);
        acc = fmaf(w1, h1v, acc);
        acc = fmaf(w2, h2v, acc);
        acc = fmaf(w3, h3v, acc);
        wsum += (w0 + w1) + (w2 + w3);
    }
    for (; j < end; ++j) {
        int s = colx[j];
        float e = as1[s * 8 + h] + adn;
        e = (e > 0.f) ? e : NEG_SLOPE * e;
        float w = __expf(e);
        acc = fmaf(w, __half2float(h1h[(size_t)s * 64 + lane]), acc);
        wsum += w;
    }
    float v = acc / (wsum + EPSV) + bias1[lane];
    helu[(size_t)n * 64 + lane] = (v > 0.f) ? v : (__expf(v) - 1.f);
}

// ---------------- Layer 2 GEMM: h2 = helu@W2 (N,64)->(N,40) ----------------
__global__ __launch_bounds__(256) void gemm2_alpha(
    const float* __restrict__ helu, const float* __restrict__ W2,
    const float* __restrict__ aS, const float* __restrict__ aD,
    __half* __restrict__ h2h, float* __restrict__ as2, float* __restrict__ ad2, int N)
{
    __shared__ float Ws[64 * 40];    // 10 KB
    __shared__ float xs[16][64];     // 4 KB
    int t = threadIdx.x;
    for (int i = t; i < 64 * 40; i += 256) Ws[i] = W2[i];
    int n0 = blockIdx.x * 16;
    for (int i = t; i < 16 * 64; i += 256) {
        int r = i >> 6, c = i & 63;
        int n = n0 + r;
        xs[r][c] = (n < N) ? helu[(size_t)n * 64 + c] : 0.f;
    }
    __syncthreads();
    int wv = t >> 6;
    int c = t & 63;
    float asc = (c < 40) ? aS[c] : 0.f;
    float adc = (c < 40) ? aD[c] : 0.f;
#pragma unroll
    for (int r = 0; r < 4; ++r) {
        int local = wv * 4 + r;
        int n = n0 + local;
        float acc = 0.f;
        if (c < 40) {
#pragma unroll
            for (int k = 0; k < 64; ++k) acc = fmaf(xs[local][k], Ws[k * 40 + c], acc);
        }
        float s = acc * asc;
        float d = acc * adc;
#pragma unroll
        for (int off = 1; off < 64; off <<= 1) {
            s += __shfl_xor(s, off, 64);
            d += __shfl_xor(d, off, 64);
        }
        if (n < N) {
            if (c < 40) h2h[(size_t)n * 40 + c] = __float2half(acc);
            if (c == 0) { as2[n] = s; ad2[n] = d; }
        }
    }
}

// ---------------- Layer 2 gather: one wave per dst node, unroll-4, fp16 h2 ----------------
__global__ __launch_bounds__(256) void gather2(
    const int* __restrict__ row_ptr, const int* __restrict__ colx,
    const float* __restrict__ as2, const float* __restrict__ ad2,
    const __half* __restrict__ h2h, const float* __restrict__ bias2,
    float* __restrict__ out, int N)
{
    int wave = (blockIdx.x * 256 + threadIdx.x) >> 6;
    int lane = threadIdx.x & 63;
    if (wave >= N) return;
    int n = wave;
    float adn = ad2[n];
    int beg = row_ptr[n], end = row_ptr[n + 1];
    float acc = 0.f, wsum = 0.f;
    bool act = (lane < 40);
    int j = beg;
    for (; j + 4 <= end; j += 4) {
        int s0 = colx[j], s1 = colx[j + 1], s2 = colx[j + 2], s3 = colx[j + 3];
        float a0 = as2[s0], a1 = as2[s1], a2 = as2[s2], a3 = as2[s3];
        float h0 = act ? __half2float(h2h[(size_t)s0 * 40 + lane]) : 0.f;
        float h1v = act ? __half2float(h2h[(size_t)s1 * 40 + lane]) : 0.f;
        float h2v = act ? __half2float(h2h[(size_t)s2 * 40 + lane]) : 0.f;
        float h3v = act ? __half2float(h2h[(size_t)s3 * 40 + lane]) : 0.f;
        float e0 = a0 + adn; e0 = (e0 > 0.f) ? e0 : NEG_SLOPE * e0;
        float e1 = a1 + adn; e1 = (e1 > 0.f) ? e1 : NEG_SLOPE * e1;
        float e2 = a2 + adn; e2 = (e2 > 0.f) ? e2 : NEG_SLOPE * e2;
        float e3 = a3 + adn; e3 = (e3 > 0.f) ? e3 : NEG_SLOPE * e3;
        float w0 = __expf(e0), w1 = __expf(e1), w2 = __expf(e2), w3 = __expf(e3);
        acc = fmaf(w0, h0, acc);
        acc = fmaf(w1, h1v, acc);
        acc = fmaf(w2, h2v, acc);
        acc = fmaf(w3, h3v, acc);
        wsum += (w0 + w1) + (w2 + w3);
    }
    for (; j < end; ++j) {
        int s = colx[j];
        float e = as2[s] + adn;
        e = (e > 0.f) ? e : NEG_SLOPE * e;
        float w = __expf(e);
        float hv = act ? __half2float(h2h[(size_t)s * 40 + lane]) : 0.f;
        acc = fmaf(w, hv, acc);
        wsum += w;
    }
    if (act)
        out[(size_t)n * 40 + lane] = acc / (wsum + EPSV) + bias2[lane];
}

extern "C" void kernel_launch(void* const* d_in, const int* in_sizes, int n_in,
                              void* d_out, int out_size, void* d_ws, size_t ws_size,
                              hipStream_t stream)
{
    const float* x   = (const float*)d_in[0];
    const int*   ei  = (const int*)d_in[1];
    const float* W1  = (const float*)d_in[3];
    const float* aS1 = (const float*)d_in[4];
    const float* aD1 = (const float*)d_in[5];
    const float* b1  = (const float*)d_in[6];
    const float* W2  = (const float*)d_in[7];
    const float* aS2 = (const float*)d_in[8];
    const float* aD2 = (const float*)d_in[9];
    const float* b2  = (const float*)d_in[10];

    int N  = in_sizes[0] / 128;
    int E  = in_sizes[1] / 2;
    int Et = E + N;
    int nbins = (N + NODES_PER_BIN - 1) >> BIN_SHIFT;

    // ---- workspace layout ----
    float* fws   = (float*)d_ws;
    float* as1   = fws;                        // N*8
    float* ad1   = as1  + (size_t)N * 8;       // N*8
    float* helu  = ad1  + (size_t)N * 8;       // N*64
    float* as2   = helu + (size_t)N * 64;      // N
    float* ad2   = as2  + (size_t)N;           // N
    __half* h1h  = (__half*)(ad2 + (size_t)N); // N*64 halves
    __half* h2h  = h1h + (size_t)N * 64;       // N*40 halves
    int*   iws     = (int*)(h2h + (size_t)N * 40);
    int*   row_ptr = iws;                      // N+1
    int*   bincnt  = row_ptr + N + 1;          // MAXBINS+1
    int*   binoff  = bincnt + MAXBINS + 1;     // MAXBINS+1
    int*   bincur  = binoff + MAXBINS + 1;     // MAXBINS
    unsigned int* binned = (unsigned int*)(bincur + MAXBINS);  // Et
    int*   colx    = (int*)(binned + Et);      // Et
    float* out     = (float*)d_out;

    const int* srcs = ei;
    const int* dsts = ei + E;

    int blocksA = (Et + CHUNK - 1) / CHUNK;

    // ---- CSR build (binned counting sort) ----
    hipMemsetAsync(bincnt, 0, (size_t)(MAXBINS + 1) * sizeof(int), stream);
    binhist<<<blocksA, 256, 0, stream>>>(dsts, bincnt, E, Et, nbins);
    binscan<<<1, 64, 0, stream>>>(bincnt, binoff, bincur, row_ptr, nbins, N, Et);
    binscatter<<<blocksA, 256, 0, stream>>>(srcs, dsts, bincur, binned, E, Et, nbins);
    binsort<<<nbins, 256, 0, stream>>>(binned, binoff, row_ptr, colx, N, nbins);

    // ---- Layer 1 ----
    gemm1_alpha<<<(N + 15) / 16, 256, 0, stream>>>(x, W1, aS1, aD1, h1h, as1, ad1, N);
    gather1<<<(N * 64 + 255) / 256, 256, 0, stream>>>(row_ptr, colx, as1, ad1, h1h, b1, helu, N);

    // ---- Layer 2 ----
    gemm2_alpha<<<(N + 15) / 16, 256, 0, stream>>>(helu, W2, aS2, aD2, h2h, as2, ad2, N);
    gather2<<<(N * 64 + 255) / 256, 256, 0, stream>>>(row_ptr, colx, as2, ad2, h2h, b2, out, N);
}

// Round 5
// 299.616 us; speedup vs baseline: 12.0940x; 1.0788x over previous
//
#include <hip/hip_runtime.h>
#include <hip/hip_fp16.h>
#include <cstdint>

#define NEG_SLOPE 0.2f
#define EPSV 1e-16f

#define BIN_SHIFT 8
#define NODES_PER_BIN 256
#define MAXBINS 512
#define CHUNK 8192

// ---------------- Layer 1 GEMM: h1 = x@W1 (N,128)->(N,64) + alpha logits ----------------
// W staged transposed + XOR-swizzled so the hot loop reads ds_read_b128 per lane.
__global__ __launch_bounds__(256) void gemm1_alpha(
    const float* __restrict__ x, const float* __restrict__ W1,
    const float* __restrict__ aS, const float* __restrict__ aD,
    __half* __restrict__ h1h, float* __restrict__ as1, float* __restrict__ ad1, int N)
{
    __shared__ float WsT[64 * 128];  // 32 KB, WsT[c][k^swz(c)]
    __shared__ float xs[16][128];    // 8 KB
    int t = threadIdx.x;
    for (int i = t; i < 128 * 64; i += 256) {
        int k = i >> 6, c = i & 63;
        WsT[c * 128 + (k ^ ((c & 7) << 2))] = W1[i];
    }
    int n0 = blockIdx.x * 16;
    for (int i = t; i < 16 * 128; i += 256) {
        int r = i >> 7, c = i & 127;
        int n = n0 + r;
        xs[r][c] = (n < N) ? x[(size_t)n * 128 + c] : 0.f;
    }
    __syncthreads();
    int wv = t >> 6;
    int col = t & 63;     // col = h*8 + d
    const float* wrow = &WsT[col * 128];
    int sw = (col & 7) << 2;
    float asc = aS[col], adc = aD[col];
#pragma unroll
    for (int r = 0; r < 4; ++r) {
        int local = wv * 4 + r;
        int n = n0 + local;
        const float4* xv4 = (const float4*)xs[local];
        float acc = 0.f;
#pragma unroll
        for (int k = 0; k < 128; k += 4) {
            float4 w4 = *(const float4*)&wrow[k ^ sw];
            float4 x4 = xv4[k >> 2];
            acc = fmaf(x4.x, w4.x, acc);
            acc = fmaf(x4.y, w4.y, acc);
            acc = fmaf(x4.z, w4.z, acc);
            acc = fmaf(x4.w, w4.w, acc);
        }
        float s = acc * asc;
        float d = acc * adc;
#pragma unroll
        for (int off = 1; off < 8; off <<= 1) {
            s += __shfl_xor(s, off, 64);
            d += __shfl_xor(d, off, 64);
        }
        if (n < N) {
            h1h[(size_t)n * 64 + col] = __float2half(acc);
            if ((col & 7) == 0) {
                as1[n * 8 + (col >> 3)] = s;
                ad1[n * 8 + (col >> 3)] = d;
            }
        }
    }
}

// ---------------- CSR build: binned counting sort ----------------
__global__ __launch_bounds__(256) void binhist(
    const int* __restrict__ dsts, int* __restrict__ bincnt, int E, int Et, int nbins)
{
    __shared__ int lh[MAXBINS];
    int t = threadIdx.x;
    for (int i = t; i < nbins; i += 256) lh[i] = 0;
    __syncthreads();
    int base = blockIdx.x * CHUNK;
#pragma unroll
    for (int r = 0; r < CHUNK / 256; ++r) {
        int i = base + r * 256 + t;
        if (i < Et) {
            int dn = (i < E) ? dsts[i] : (i - E);
            atomicAdd(&lh[dn >> BIN_SHIFT], 1);
        }
    }
    __syncthreads();
    for (int i = t; i < nbins; i += 256)
        if (lh[i]) atomicAdd(&bincnt[i], lh[i]);
}

__global__ void binscan(const int* __restrict__ bincnt, int* __restrict__ binoff,
                        int* __restrict__ bincur, int* __restrict__ row_ptr,
                        int nbins, int N, int Et)
{
    if (threadIdx.x == 0 && blockIdx.x == 0) {
        int run = 0;
        for (int b = 0; b < nbins; ++b) { binoff[b] = run; bincur[b] = run; run += bincnt[b]; }
        binoff[nbins] = run;
        row_ptr[N] = Et;
    }
}

__global__ __launch_bounds__(256) void binscatter(
    const int* __restrict__ srcs, const int* __restrict__ dsts,
    int* __restrict__ bincur, unsigned int* __restrict__ binned, int E, int Et, int nbins)
{
    __shared__ int lh[MAXBINS];
    __shared__ int gbase[MAXBINS];
    __shared__ int lcur[MAXBINS];
    int t = threadIdx.x;
    for (int i = t; i < nbins; i += 256) lh[i] = 0;
    __syncthreads();
    int base = blockIdx.x * CHUNK;
#pragma unroll
    for (int r = 0; r < CHUNK / 256; ++r) {
        int i = base + r * 256 + t;
        if (i < Et) {
            int dn = (i < E) ? dsts[i] : (i - E);
            atomicAdd(&lh[dn >> BIN_SHIFT], 1);
        }
    }
    __syncthreads();
    for (int i = t; i < nbins; i += 256) {
        gbase[i] = lh[i] ? atomicAdd(&bincur[i], lh[i]) : 0;
        lcur[i] = 0;
    }
    __syncthreads();
#pragma unroll
    for (int r = 0; r < CHUNK / 256; ++r) {
        int i = base + r * 256 + t;
        if (i < Et) {
            int s, dn;
            if (i < E) { s = srcs[i]; dn = dsts[i]; }
            else       { s = i - E;   dn = s; }
            int b = dn >> BIN_SHIFT;
            int li = atomicAdd(&lcur[b], 1);
            binned[gbase[b] + li] = ((unsigned)(dn & (NODES_PER_BIN - 1)) << 24) | (unsigned)s;
        }
    }
}

__global__ __launch_bounds__(256) void binsort(
    const unsigned int* __restrict__ binned, const int* __restrict__ binoff,
    int* __restrict__ row_ptr, int* __restrict__ colx, int N, int nbins)
{
    __shared__ int lh[NODES_PER_BIN];
    __shared__ int lcur[NODES_PER_BIN];
    int b = blockIdx.x, t = threadIdx.x;
    int beg = binoff[b], end = binoff[b + 1];
    lh[t] = 0;
    __syncthreads();
    for (int j = beg + t; j < end; j += 256)
        atomicAdd(&lh[binned[j] >> 24], 1);
    __syncthreads();
    int own = lh[t];
    for (int off = 1; off < 256; off <<= 1) {
        int y = (t >= off) ? lh[t - off] : 0;
        __syncthreads();
        lh[t] += y;
        __syncthreads();
    }
    int excl = lh[t] - own;
    int gnode = (b << BIN_SHIFT) + t;
    if (gnode < N) row_ptr[gnode] = beg + excl;
    lcur[t] = excl;
    __syncthreads();
    for (int j = beg + t; j < end; j += 256) {
        unsigned p = binned[j];
        int pos = atomicAdd(&lcur[p >> 24], 1);
        colx[beg + pos] = (int)(p & 0xFFFFFF);
    }
}

// ---------------- Layer 1 gather: wave per node, lane-batched colx, shfl-driven ----------------
__global__ __launch_bounds__(256) void gather1(
    const int* __restrict__ row_ptr, const int* __restrict__ colx,
    const float* __restrict__ as1, const float* __restrict__ ad1,
    const __half* __restrict__ h1h, const float* __restrict__ bias1,
    float* __restrict__ helu, int N)
{
    int wave = (blockIdx.x * 256 + threadIdx.x) >> 6;
    int lane = threadIdx.x & 63;
    if (wave >= N) return;
    int n = wave;
    int h = lane >> 3;
    float adn = ad1[n * 8 + h];
    int beg = row_ptr[n], end = row_ptr[n + 1];
    float acc = 0.f, wsum = 0.f;
    for (int cb = beg; cb < end; cb += 64) {
        int cnt = min(64, end - cb);
        int sv = (cb + lane < end) ? colx[cb + lane] : 0;
        int k = 0;
        for (; k + 4 <= cnt; k += 4) {
            int s0 = __shfl(sv, k, 64);
            int s1 = __shfl(sv, k + 1, 64);
            int s2 = __shfl(sv, k + 2, 64);
            int s3 = __shfl(sv, k + 3, 64);
            float a0 = as1[s0 * 8 + h];
            float a1 = as1[s1 * 8 + h];
            float a2 = as1[s2 * 8 + h];
            float a3 = as1[s3 * 8 + h];
            float h0 = __half2float(h1h[(size_t)s0 * 64 + lane]);
            float h1v = __half2float(h1h[(size_t)s1 * 64 + lane]);
            float h2v = __half2float(h1h[(size_t)s2 * 64 + lane]);
            float h3v = __half2float(h1h[(size_t)s3 * 64 + lane]);
            float e0 = a0 + adn; e0 = (e0 > 0.f) ? e0 : NEG_SLOPE * e0;
            float e1 = a1 + adn; e1 = (e1 > 0.f) ? e1 : NEG_SLOPE * e1;
            float e2 = a2 + adn; e2 = (e2 > 0.f) ? e2 : NEG_SLOPE * e2;
            float e3 = a3 + adn; e3 = (e3 > 0.f) ? e3 : NEG_SLOPE * e3;
            float w0 = __expf(e0), w1 = __expf(e1), w2 = __expf(e2), w3 = __expf(e3);
            acc = fmaf(w0, h0, acc);
            acc = fmaf(w1, h1v, acc);
            acc = fmaf(w2, h2v, acc);
            acc = fmaf(w3, h3v, acc);
            wsum += (w0 + w1) + (w2 + w3);
        }
        for (; k < cnt; ++k) {
            int s = __shfl(sv, k, 64);
            float e = as1[s * 8 + h] + adn;
            e = (e > 0.f) ? e : NEG_SLOPE * e;
            float w = __expf(e);
            acc = fmaf(w, __half2float(h1h[(size_t)s * 64 + lane]), acc);
            wsum += w;
        }
    }
    float v = acc / (wsum + EPSV) + bias1[lane];
    helu[(size_t)n * 64 + lane] = (v > 0.f) ? v : (__expf(v) - 1.f);
}

// ---------------- Layer 2 GEMM: h2 = helu@W2 (N,64)->(N,40) ----------------
__global__ __launch_bounds__(256) void gemm2_alpha(
    const float* __restrict__ helu, const float* __restrict__ W2,
    const float* __restrict__ aS, const float* __restrict__ aD,
    __half* __restrict__ h2h, float* __restrict__ as2, float* __restrict__ ad2, int N)
{
    __shared__ float WsT[40 * 64];   // 10 KB, WsT[c][k^swz(c)]
    __shared__ float xs[16][64];     // 4 KB
    int t = threadIdx.x;
    for (int i = t; i < 64 * 40; i += 256) {
        int k = i / 40, c = i - k * 40;
        WsT[c * 64 + (k ^ ((c & 7) << 2))] = W2[i];
    }
    int n0 = blockIdx.x * 16;
    for (int i = t; i < 16 * 64; i += 256) {
        int r = i >> 6, c = i & 63;
        int n = n0 + r;
        xs[r][c] = (n < N) ? helu[(size_t)n * 64 + c] : 0.f;
    }
    __syncthreads();
    int wv = t >> 6;
    int c = t & 63;
    bool act = (c < 40);
    const float* wrow = &WsT[(act ? c : 0) * 64];
    int sw = (c & 7) << 2;
    float asc = act ? aS[c] : 0.f;
    float adc = act ? aD[c] : 0.f;
#pragma unroll
    for (int r = 0; r < 4; ++r) {
        int local = wv * 4 + r;
        int n = n0 + local;
        const float4* xv4 = (const float4*)xs[local];
        float acc = 0.f;
#pragma unroll
        for (int k = 0; k < 64; k += 4) {
            float4 w4 = *(const float4*)&wrow[k ^ sw];
            float4 x4 = xv4[k >> 2];
            acc = fmaf(x4.x, w4.x, acc);
            acc = fmaf(x4.y, w4.y, acc);
            acc = fmaf(x4.z, w4.z, acc);
            acc = fmaf(x4.w, w4.w, acc);
        }
        if (!act) acc = 0.f;
        float s = acc * asc;
        float d = acc * adc;
#pragma unroll
        for (int off = 1; off < 64; off <<= 1) {
            s += __shfl_xor(s, off, 64);
            d += __shfl_xor(d, off, 64);
        }
        if (n < N) {
            if (act) h2h[(size_t)n * 40 + c] = __float2half(acc);
            if (c == 0) { as2[n] = s; ad2[n] = d; }
        }
    }
}

// ---------------- Layer 2 gather: wave per node, lane-batched colx ----------------
__global__ __launch_bounds__(256) void gather2(
    const int* __restrict__ row_ptr, const int* __restrict__ colx,
    const float* __restrict__ as2, const float* __restrict__ ad2,
    const __half* __restrict__ h2h, const float* __restrict__ bias2,
    float* __restrict__ out, int N)
{
    int wave = (blockIdx.x * 256 + threadIdx.x) >> 6;
    int lane = threadIdx.x & 63;
    if (wave >= N) return;
    int n = wave;
    float adn = ad2[n];
    int beg = row_ptr[n], end = row_ptr[n + 1];
    float acc = 0.f, wsum = 0.f;
    bool act = (lane < 40);
    for (int cb = beg; cb < end; cb += 64) {
        int cnt = min(64, end - cb);
        int sv = (cb + lane < end) ? colx[cb + lane] : 0;
        int k = 0;
        for (; k + 4 <= cnt; k += 4) {
            int s0 = __shfl(sv, k, 64);
            int s1 = __shfl(sv, k + 1, 64);
            int s2 = __shfl(sv, k + 2, 64);
            int s3 = __shfl(sv, k + 3, 64);
            float a0 = as2[s0], a1 = as2[s1], a2 = as2[s2], a3 = as2[s3];
            float h0 = act ? __half2float(h2h[(size_t)s0 * 40 + lane]) : 0.f;
            float h1v = act ? __half2float(h2h[(size_t)s1 * 40 + lane]) : 0.f;
            float h2v = act ? __half2float(h2h[(size_t)s2 * 40 + lane]) : 0.f;
            float h3v = act ? __half2float(h2h[(size_t)s3 * 40 + lane]) : 0.f;
            float e0 = a0 + adn; e0 = (e0 > 0.f) ? e0 : NEG_SLOPE * e0;
            float e1 = a1 + adn; e1 = (e1 > 0.f) ? e1 : NEG_SLOPE * e1;
            float e2 = a2 + adn; e2 = (e2 > 0.f) ? e2 : NEG_SLOPE * e2;
            float e3 = a3 + adn; e3 = (e3 > 0.f) ? e3 : NEG_SLOPE * e3;
            float w0 = __expf(e0), w1 = __expf(e1), w2 = __expf(e2), w3 = __expf(e3);
            acc = fmaf(w0, h0, acc);
            acc = fmaf(w1, h1v, acc);
            acc = fmaf(w2, h2v, acc);
            acc = fmaf(w3, h3v, acc);
            wsum += (w0 + w1) + (w2 + w3);
        }
        for (; k < cnt; ++k) {
            int s = __shfl(sv, k, 64);
            float e = as2[s] + adn;
            e = (e > 0.f) ? e : NEG_SLOPE * e;
            float w = __expf(e);
            float hv = act ? __half2float(h2h[(size_t)s * 40 + lane]) : 0.f;
            acc = fmaf(w, hv, acc);
            wsum += w;
        }
    }
    if (act)
        out[(size_t)n * 40 + lane] = acc / (wsum + EPSV) + bias2[lane];
}

extern "C" void kernel_launch(void* const* d_in, const int* in_sizes, int n_in,
                              void* d_out, int out_size, void* d_ws, size_t ws_size,
                              hipStream_t stream)
{
    const float* x   = (const float*)d_in[0];
    const int*   ei  = (const int*)d_in[1];
    const float* W1  = (const float*)d_in[3];
    const float* aS1 = (const float*)d_in[4];
    const float* aD1 = (const float*)d_in[5];
    const float* b1  = (const float*)d_in[6];
    const float* W2  = (const float*)d_in[7];
    const float* aS2 = (const float*)d_in[8];
    const float* aD2 = (const float*)d_in[9];
    const float* b2  = (const float*)d_in[10];

    int N  = in_sizes[0] / 128;
    int E  = in_sizes[1] / 2;
    int Et = E + N;
    int nbins = (N + NODES_PER_BIN - 1) >> BIN_SHIFT;

    // ---- workspace layout ----
    float* fws   = (float*)d_ws;
    float* as1   = fws;                        // N*8
    float* ad1   = as1  + (size_t)N * 8;       // N*8
    float* helu  = ad1  + (size_t)N * 8;       // N*64
    float* as2   = helu + (size_t)N * 64;      // N
    float* ad2   = as2  + (size_t)N;           // N
    __half* h1h  = (__half*)(ad2 + (size_t)N); // N*64 halves
    __half* h2h  = h1h + (size_t)N * 64;       // N*40 halves
    int*   iws     = (int*)(h2h + (size_t)N * 40);
    int*   row_ptr = iws;                      // N+1
    int*   bincnt  = row_ptr + N + 1;          // MAXBINS+1
    int*   binoff  = bincnt + MAXBINS + 1;     // MAXBINS+1
    int*   bincur  = binoff + MAXBINS + 1;     // MAXBINS
    unsigned int* binned = (unsigned int*)(bincur + MAXBINS);  // Et
    int*   colx    = (int*)(binned + Et);      // Et
    float* out     = (float*)d_out;

    const int* srcs = ei;
    const int* dsts = ei + E;

    int blocksA = (Et + CHUNK - 1) / CHUNK;

    // ---- CSR build (binned counting sort) ----
    hipMemsetAsync(bincnt, 0, (size_t)(MAXBINS + 1) * sizeof(int), stream);
    binhist<<<blocksA, 256, 0, stream>>>(dsts, bincnt, E, Et, nbins);
    binscan<<<1, 64, 0, stream>>>(bincnt, binoff, bincur, row_ptr, nbins, N, Et);
    binscatter<<<blocksA, 256, 0, stream>>>(srcs, dsts, bincur, binned, E, Et, nbins);
    binsort<<<nbins, 256, 0, stream>>>(binned, binoff, row_ptr, colx, N, nbins);

    // ---- Layer 1 ----
    gemm1_alpha<<<(N + 15) / 16, 256, 0, stream>>>(x, W1, aS1, aD1, h1h, as1, ad1, N);
    gather1<<<(N * 64 + 255) / 256, 256, 0, stream>>>(row_ptr, colx, as1, ad1, h1h, b1, helu, N);

    // ---- Layer 2 ----
    gemm2_alpha<<<(N + 15) / 16, 256, 0, stream>>>(helu, W2, aS2, aD2, h2h, as2, ad2, N);
    gather2<<<(N * 64 + 255) / 256, 256, 0, stream>>>(row_ptr, colx, as2, ad2, h2h, b2, out, N);
}

// Round 7
// 256.025 us; speedup vs baseline: 14.1531x; 1.1703x over previous
//
#include <hip/hip_runtime.h>
#include <hip/hip_fp16.h>
#include <cstdint>

#define NEG_SLOPE 0.2f
#define EPSV 1e-16f

#define BIN_SHIFT 8
#define NODES_PER_BIN 256
#define MAXBINS 512
#define CHUNK 8192

// ---------------- Layer 1 GEMM: h1 = x@W1 (N,128)->(N,64) + alpha logits ----------------
__global__ __launch_bounds__(256) void gemm1_alpha(
    const float* __restrict__ x, const float* __restrict__ W1,
    const float* __restrict__ aS, const float* __restrict__ aD,
    __half* __restrict__ h1h, float* __restrict__ as1, float* __restrict__ ad1, int N)
{
    __shared__ float WsT[64 * 128];  // 32 KB, WsT[c][k^swz(c)]
    __shared__ float xs[16][128];    // 8 KB
    int t = threadIdx.x;
    for (int i = t; i < 128 * 64; i += 256) {
        int k = i >> 6, c = i & 63;
        WsT[c * 128 + (k ^ ((c & 7) << 2))] = W1[i];
    }
    int n0 = blockIdx.x * 16;
    for (int i = t; i < 16 * 128; i += 256) {
        int r = i >> 7, c = i & 127;
        int n = n0 + r;
        xs[r][c] = (n < N) ? x[(size_t)n * 128 + c] : 0.f;
    }
    __syncthreads();
    int wv = t >> 6;
    int col = t & 63;     // col = h*8 + d
    const float* wrow = &WsT[col * 128];
    int sw = (col & 7) << 2;
    float asc = aS[col], adc = aD[col];
#pragma unroll
    for (int r = 0; r < 4; ++r) {
        int local = wv * 4 + r;
        int n = n0 + local;
        const float4* xv4 = (const float4*)xs[local];
        float acc = 0.f;
#pragma unroll
        for (int k = 0; k < 128; k += 4) {
            float4 w4 = *(const float4*)&wrow[k ^ sw];
            float4 x4 = xv4[k >> 2];
            acc = fmaf(x4.x, w4.x, acc);
            acc = fmaf(x4.y, w4.y, acc);
            acc = fmaf(x4.z, w4.z, acc);
            acc = fmaf(x4.w, w4.w, acc);
        }
        float s = acc * asc;
        float d = acc * adc;
#pragma unroll
        for (int off = 1; off < 8; off <<= 1) {
            s += __shfl_xor(s, off, 64);
            d += __shfl_xor(d, off, 64);
        }
        if (n < N) {
            h1h[(size_t)n * 64 + col] = __float2half(acc);
            if ((col & 7) == 0) {
                as1[n * 8 + (col >> 3)] = s;
                ad1[n * 8 + (col >> 3)] = d;
            }
        }
    }
}

// ---------------- CSR build: binned counting sort ----------------
__global__ __launch_bounds__(256) void binhist(
    const int* __restrict__ dsts, int* __restrict__ bincnt, int E, int Et, int nbins)
{
    __shared__ int lh[MAXBINS];
    int t = threadIdx.x;
    for (int i = t; i < nbins; i += 256) lh[i] = 0;
    __syncthreads();
    int base = blockIdx.x * CHUNK;
#pragma unroll
    for (int r = 0; r < CHUNK / 256; ++r) {
        int i = base + r * 256 + t;
        if (i < Et) {
            int dn = (i < E) ? dsts[i] : (i - E);
            atomicAdd(&lh[dn >> BIN_SHIFT], 1);
        }
    }
    __syncthreads();
    for (int i = t; i < nbins; i += 256)
        if (lh[i]) atomicAdd(&bincnt[i], lh[i]);
}

__global__ void binscan(const int* __restrict__ bincnt, int* __restrict__ binoff,
                        int* __restrict__ bincur, int* __restrict__ row_ptr,
                        int nbins, int N, int Et)
{
    if (threadIdx.x == 0 && blockIdx.x == 0) {
        int run = 0;
        for (int b = 0; b < nbins; ++b) { binoff[b] = run; bincur[b] = run; run += bincnt[b]; }
        binoff[nbins] = run;
        row_ptr[N] = Et;
    }
}

__global__ __launch_bounds__(256) void binscatter(
    const int* __restrict__ srcs, const int* __restrict__ dsts,
    int* __restrict__ bincur, unsigned int* __restrict__ binned, int E, int Et, int nbins)
{
    __shared__ int lh[MAXBINS];
    __shared__ int gbase[MAXBINS];
    __shared__ int lcur[MAXBINS];
    int t = threadIdx.x;
    for (int i = t; i < nbins; i += 256) lh[i] = 0;
    __syncthreads();
    int base = blockIdx.x * CHUNK;
#pragma unroll
    for (int r = 0; r < CHUNK / 256; ++r) {
        int i = base + r * 256 + t;
        if (i < Et) {
            int dn = (i < E) ? dsts[i] : (i - E);
            atomicAdd(&lh[dn >> BIN_SHIFT], 1);
        }
    }
    __syncthreads();
    for (int i = t; i < nbins; i += 256) {
        gbase[i] = lh[i] ? atomicAdd(&bincur[i], lh[i]) : 0;
        lcur[i] = 0;
    }
    __syncthreads();
#pragma unroll
    for (int r = 0; r < CHUNK / 256; ++r) {
        int i = base + r * 256 + t;
        if (i < Et) {
            int s, dn;
            if (i < E) { s = srcs[i]; dn = dsts[i]; }
            else       { s = i - E;   dn = s; }
            int b = dn >> BIN_SHIFT;
            int li = atomicAdd(&lcur[b], 1);
            binned[gbase[b] + li] = ((unsigned)(dn & (NODES_PER_BIN - 1)) << 24) | (unsigned)s;
        }
    }
}

__global__ __launch_bounds__(256) void binsort(
    const unsigned int* __restrict__ binned, const int* __restrict__ binoff,
    int* __restrict__ row_ptr, int* __restrict__ colx, int N, int nbins)
{
    __shared__ int lh[NODES_PER_BIN];
    __shared__ int lcur[NODES_PER_BIN];
    int b = blockIdx.x, t = threadIdx.x;
    int beg = binoff[b], end = binoff[b + 1];
    lh[t] = 0;
    __syncthreads();
    for (int j = beg + t; j < end; j += 256)
        atomicAdd(&lh[binned[j] >> 24], 1);
    __syncthreads();
    int own = lh[t];
    for (int off = 1; off < 256; off <<= 1) {
        int y = (t >= off) ? lh[t - off] : 0;
        __syncthreads();
        lh[t] += y;
        __syncthreads();
    }
    int excl = lh[t] - own;
    int gnode = (b << BIN_SHIFT) + t;
    if (gnode < N) row_ptr[gnode] = beg + excl;
    lcur[t] = excl;
    __syncthreads();
    for (int j = beg + t; j < end; j += 256) {
        unsigned p = binned[j];
        int pos = atomicAdd(&lcur[p >> 24], 1);
        colx[beg + pos] = (int)(p & 0xFFFFFF);
    }
}

// ---------------- Layer 1 gather: 2 edges/wave, uniform loop + predicated weights ----------------
__global__ __launch_bounds__(256) void gather1(
    const int* __restrict__ row_ptr, const int* __restrict__ colx,
    const float* __restrict__ as1, const float* __restrict__ ad1,
    const __half2* __restrict__ h1v, const float2* __restrict__ bias1,
    float2* __restrict__ helu, int N)
{
    int wave = (blockIdx.x * 256 + threadIdx.x) >> 6;
    if (wave >= N) return;
    int lane = threadIdx.x & 63;
    int half = lane >> 5;
    int sub = lane & 31;          // owns dims 2*sub, 2*sub+1
    int hh = sub >> 2;            // head of those dims
    int n = wave;
    float adn = ad1[n * 8 + hh];
    int beg = row_ptr[n], end = row_ptr[n + 1];
    float2 acc = make_float2(0.f, 0.f);
    float wsum = 0.f;
    for (int cb = beg; cb < end; cb += 64) {
        int cnt = min(64, end - cb);
        int sv = (cb + lane < end) ? colx[cb + lane] : 0;
        int iters = (cnt + 3) >> 2;   // uniform across wave
        for (int i = 0; i < iters; ++i) {
            int k0 = (i << 2) + half;
            int k1 = k0 + 2;
            int sA = __shfl(sv, k0, 64);   // all lanes active: defined
            int sB = __shfl(sv, k1, 64);   // OOB lanes hold sv=0 (valid node)
            float aA = as1[sA * 8 + hh];
            float aB = as1[sB * 8 + hh];
            __half2 hA = h1v[(size_t)sA * 32 + sub];
            __half2 hB = h1v[(size_t)sB * 32 + sub];
            float eA = aA + adn; eA = (eA > 0.f) ? eA : NEG_SLOPE * eA;
            float eB = aB + adn; eB = (eB > 0.f) ? eB : NEG_SLOPE * eB;
            float wA = (k0 < cnt) ? __expf(eA) : 0.f;
            float wB = (k1 < cnt) ? __expf(eB) : 0.f;
            float2 fA = __half22float2(hA);
            float2 fB = __half22float2(hB);
            acc.x = fmaf(wA, fA.x, acc.x);
            acc.y = fmaf(wA, fA.y, acc.y);
            acc.x = fmaf(wB, fB.x, acc.x);
            acc.y = fmaf(wB, fB.y, acc.y);
            wsum += wA + wB;
        }
    }
    acc.x += __shfl_xor(acc.x, 32, 64);
    acc.y += __shfl_xor(acc.y, 32, 64);
    wsum += __shfl_xor(wsum, 32, 64);
    if (half == 0) {
        float2 b = bias1[sub];
        float inv = 1.f / (wsum + EPSV);
        float vx = acc.x * inv + b.x;
        float vy = acc.y * inv + b.y;
        vx = (vx > 0.f) ? vx : (__expf(vx) - 1.f);
        vy = (vy > 0.f) ? vy : (__expf(vy) - 1.f);
        helu[(size_t)n * 32 + sub] = make_float2(vx, vy);
    }
}

// ---------------- Layer 2 GEMM: h2 = helu@W2 (N,64)->(N,40) ----------------
__global__ __launch_bounds__(256) void gemm2_alpha(
    const float* __restrict__ helu, const float* __restrict__ W2,
    const float* __restrict__ aS, const float* __restrict__ aD,
    __half* __restrict__ h2h, float* __restrict__ as2, float* __restrict__ ad2, int N)
{
    __shared__ float WsT[40 * 64];   // 10 KB, WsT[c][k^swz(c)]
    __shared__ float xs[16][64];     // 4 KB
    int t = threadIdx.x;
    for (int i = t; i < 64 * 40; i += 256) {
        int k = i / 40, c = i - k * 40;
        WsT[c * 64 + (k ^ ((c & 7) << 2))] = W2[i];
    }
    int n0 = blockIdx.x * 16;
    for (int i = t; i < 16 * 64; i += 256) {
        int r = i >> 6, c = i & 63;
        int n = n0 + r;
        xs[r][c] = (n < N) ? helu[(size_t)n * 64 + c] : 0.f;
    }
    __syncthreads();
    int wv = t >> 6;
    int c = t & 63;
    bool act = (c < 40);
    const float* wrow = &WsT[(act ? c : 0) * 64];
    int sw = (c & 7) << 2;
    float asc = act ? aS[c] : 0.f;
    float adc = act ? aD[c] : 0.f;
#pragma unroll
    for (int r = 0; r < 4; ++r) {
        int local = wv * 4 + r;
        int n = n0 + local;
        const float4* xv4 = (const float4*)xs[local];
        float acc = 0.f;
#pragma unroll
        for (int k = 0; k < 64; k += 4) {
            float4 w4 = *(const float4*)&wrow[k ^ sw];
            float4 x4 = xv4[k >> 2];
            acc = fmaf(x4.x, w4.x, acc);
            acc = fmaf(x4.y, w4.y, acc);
            acc = fmaf(x4.z, w4.z, acc);
            acc = fmaf(x4.w, w4.w, acc);
        }
        if (!act) acc = 0.f;
        float s = acc * asc;
        float d = acc * adc;
#pragma unroll
        for (int off = 1; off < 64; off <<= 1) {
            s += __shfl_xor(s, off, 64);
            d += __shfl_xor(d, off, 64);
        }
        if (n < N) {
            if (act) h2h[(size_t)n * 40 + c] = __float2half(acc);
            if (c == 0) { as2[n] = s; ad2[n] = d; }
        }
    }
}

// ---------------- Layer 2 gather: 2 edges/wave, uniform loop + predicated weights ----------------
__global__ __launch_bounds__(256) void gather2(
    const int* __restrict__ row_ptr, const int* __restrict__ colx,
    const float* __restrict__ as2, const float* __restrict__ ad2,
    const __half2* __restrict__ h2v, const float2* __restrict__ bias2,
    float2* __restrict__ out, int N)
{
    int wave = (blockIdx.x * 256 + threadIdx.x) >> 6;
    if (wave >= N) return;
    int lane = threadIdx.x & 63;
    int half = lane >> 5;
    int sub = lane & 31;          // owns dims 2*sub, 2*sub+1 (sub<20 active)
    bool act = (sub < 20);
    int n = wave;
    float adn = ad2[n];
    int beg = row_ptr[n], end = row_ptr[n + 1];
    float2 acc = make_float2(0.f, 0.f);
    float wsum = 0.f;
    int subc = act ? sub : 0;
    for (int cb = beg; cb < end; cb += 64) {
        int cnt = min(64, end - cb);
        int sv = (cb + lane < end) ? colx[cb + lane] : 0;
        int iters = (cnt + 3) >> 2;   // uniform across wave
        for (int i = 0; i < iters; ++i) {
            int k0 = (i << 2) + half;
            int k1 = k0 + 2;
            int sA = __shfl(sv, k0, 64);
            int sB = __shfl(sv, k1, 64);
            float aA = as2[sA], aB = as2[sB];
            __half2 hA = h2v[(size_t)sA * 20 + subc];
            __half2 hB = h2v[(size_t)sB * 20 + subc];
            float eA = aA + adn; eA = (eA > 0.f) ? eA : NEG_SLOPE * eA;
            float eB = aB + adn; eB = (eB > 0.f) ? eB : NEG_SLOPE * eB;
            float wA = (k0 < cnt) ? __expf(eA) : 0.f;
            float wB = (k1 < cnt) ? __expf(eB) : 0.f;
            float2 fA = __half22float2(hA);
            float2 fB = __half22float2(hB);
            acc.x = fmaf(wA, fA.x, acc.x);
            acc.y = fmaf(wA, fA.y, acc.y);
            acc.x = fmaf(wB, fB.x, acc.x);
            acc.y = fmaf(wB, fB.y, acc.y);
            wsum += wA + wB;
        }
    }
    acc.x += __shfl_xor(acc.x, 32, 64);
    acc.y += __shfl_xor(acc.y, 32, 64);
    wsum += __shfl_xor(wsum, 32, 64);
    if (half == 0 && act) {
        float2 b = bias2[sub];
        float inv = 1.f / (wsum + EPSV);
        out[(size_t)n * 20 + sub] = make_float2(acc.x * inv + b.x, acc.y * inv + b.y);
    }
}

extern "C" void kernel_launch(void* const* d_in, const int* in_sizes, int n_in,
                              void* d_out, int out_size, void* d_ws, size_t ws_size,
                              hipStream_t stream)
{
    const float* x   = (const float*)d_in[0];
    const int*   ei  = (const int*)d_in[1];
    const float* W1  = (const float*)d_in[3];
    const float* aS1 = (const float*)d_in[4];
    const float* aD1 = (const float*)d_in[5];
    const float* b1  = (const float*)d_in[6];
    const float* W2  = (const float*)d_in[7];
    const float* aS2 = (const float*)d_in[8];
    const float* aD2 = (const float*)d_in[9];
    const float* b2  = (const float*)d_in[10];

    int N  = in_sizes[0] / 128;
    int E  = in_sizes[1] / 2;
    int Et = E + N;
    int nbins = (N + NODES_PER_BIN - 1) >> BIN_SHIFT;

    // ---- workspace layout ----
    float* fws   = (float*)d_ws;
    float* as1   = fws;                        // N*8
    float* ad1   = as1  + (size_t)N * 8;       // N*8
    float* helu  = ad1  + (size_t)N * 8;       // N*64
    float* as2   = helu + (size_t)N * 64;      // N
    float* ad2   = as2  + (size_t)N;           // N
    __half* h1h  = (__half*)(ad2 + (size_t)N); // N*64 halves
    __half* h2h  = h1h + (size_t)N * 64;       // N*40 halves
    int*   iws     = (int*)(h2h + (size_t)N * 40);
    int*   row_ptr = iws;                      // N+1
    int*   bincnt  = row_ptr + N + 1;          // MAXBINS+1
    int*   binoff  = bincnt + MAXBINS + 1;     // MAXBINS+1
    int*   bincur  = binoff + MAXBINS + 1;     // MAXBINS
    unsigned int* binned = (unsigned int*)(bincur + MAXBINS);  // Et
    int*   colx    = (int*)(binned + Et);      // Et
    float* out     = (float*)d_out;

    const int* srcs = ei;
    const int* dsts = ei + E;

    int blocksA = (Et + CHUNK - 1) / CHUNK;

    // ---- CSR build (binned counting sort) ----
    hipMemsetAsync(bincnt, 0, (size_t)(MAXBINS + 1) * sizeof(int), stream);
    binhist<<<blocksA, 256, 0, stream>>>(dsts, bincnt, E, Et, nbins);
    binscan<<<1, 64, 0, stream>>>(bincnt, binoff, bincur, row_ptr, nbins, N, Et);
    binscatter<<<blocksA, 256, 0, stream>>>(srcs, dsts, bincur, binned, E, Et, nbins);
    binsort<<<nbins, 256, 0, stream>>>(binned, binoff, row_ptr, colx, N, nbins);

    // ---- Layer 1 ----
    gemm1_alpha<<<(N + 15) / 16, 256, 0, stream>>>(x, W1, aS1, aD1, h1h, as1, ad1, N);
    gather1<<<(N * 64 + 255) / 256, 256, 0, stream>>>(row_ptr, colx, as1, ad1,
        (const __half2*)h1h, (const float2*)b1, (float2*)helu, N);

    // ---- Layer 2 ----
    gemm2_alpha<<<(N + 15) / 16, 256, 0, stream>>>(helu, W2, aS2, aD2, h2h, as2, ad2, N);
    gather2<<<(N * 64 + 255) / 256, 256, 0, stream>>>(row_ptr, colx, as2, ad2,
        (const __half2*)h2h, (const float2*)b2, (float2*)out, N);
}